// Round 1
// baseline (185.772 us; speedup 1.0000x reference)
//
#include <hip/hip_runtime.h>

// out[b,a,x,y] = -C0 * sum_{s,r} s[b,s,x,y] * L[s,r,a] * Fn[b,r,x,y]
// Fn = periodic 4-neighbor sum of s over the (x,y) lattice.
// L is the fixed SO(3) generator set: L[s][r][a] = -eps_{sra} (antisymmetric),
// so the einsum collapses to a cross product out = C0 * (s x Fn).
// We load the 6 nonzero L entries from Lp (not hard-coded) and fold -C0 in.
//
// Mapping: one wave (64 lanes) = one full x-row; 8 floats (2 float4) per lane
// cover Y=512. y-edge neighbors (incl. periodic wrap) come from __shfl of the
// adjacent lane -> zero uncoalesced scalar loads; every VMEM op is a full
// 1KB wave-coherent dwordx4.

constexpr int B = 32, X = 512, Y = 512;
constexpr int XY = X * Y;

__global__ __launch_bounds__(256)
void psi0_kernel(const float* __restrict__ s,
                 const float* __restrict__ C0p,
                 const float* __restrict__ Lp,
                 float* __restrict__ out)
{
    const int tid  = threadIdx.x;
    const int lane = tid & 63;
    const int wv   = tid >> 6;           // 4 waves per block, one x-row each
    const int bid  = blockIdx.x;
    const int b    = bid >> 7;           // X/4 = 128 row-quads per batch
    const int x    = ((bid & 127) << 2) + wv;
    const int y0   = lane << 3;          // 8 floats/lane * 64 lanes = 512 = Y

    const int xm = (x == 0)     ? X - 1 : x - 1;
    const int xp = (x == X - 1) ? 0     : x + 1;

    const float C0 = C0p[0];
    // Nonzero entries of L[s][r][a] at Lp[s*9 + r*3 + a], -C0 folded in:
    const float cA0 = -C0 * Lp[15];  // a=0: (s=1,r=2)
    const float cB0 = -C0 * Lp[21];  // a=0: (s=2,r=1)
    const float cA1 = -C0 * Lp[7];   // a=1: (s=0,r=2)
    const float cB1 = -C0 * Lp[19];  // a=1: (s=2,r=0)
    const float cA2 = -C0 * Lp[5];   // a=2: (s=0,r=1)
    const float cB2 = -C0 * Lp[11];  // a=2: (s=1,r=0)

    const size_t baseB = (size_t)b * 3 * XY;
    const size_t offC  = (size_t)x  * Y + y0;
    const size_t offU  = (size_t)xm * Y + y0;
    const size_t offD  = (size_t)xp * Y + y0;

    float sc[3][8];
    float Fn[3][8];

    #pragma unroll
    for (int c = 0; c < 3; ++c) {
        const float* p = s + baseB + (size_t)c * XY;
        const float4 c0 = *(const float4*)(p + offC);
        const float4 c1 = *(const float4*)(p + offC + 4);
        const float4 u0 = *(const float4*)(p + offU);
        const float4 u1 = *(const float4*)(p + offU + 4);
        const float4 d0 = *(const float4*)(p + offD);
        const float4 d1 = *(const float4*)(p + offD + 4);

        // Periodic y-neighbors across lanes: lane l owns y in [8l, 8l+8).
        // left edge (y0-1)  -> lane (l-1) mod 64, its element 7 (c1.w)
        // right edge (y0+8) -> lane (l+1) mod 64, its element 0 (c0.x)
        const float lf = __shfl(c1.w, (lane + 63) & 63, 64);
        const float rt = __shfl(c0.x, (lane + 1) & 63, 64);

        sc[c][0] = c0.x; sc[c][1] = c0.y; sc[c][2] = c0.z; sc[c][3] = c0.w;
        sc[c][4] = c1.x; sc[c][5] = c1.y; sc[c][6] = c1.z; sc[c][7] = c1.w;

        Fn[c][0] = u0.x + d0.x + lf   + c0.y;
        Fn[c][1] = u0.y + d0.y + c0.x + c0.z;
        Fn[c][2] = u0.z + d0.z + c0.y + c0.w;
        Fn[c][3] = u0.w + d0.w + c0.z + c1.x;
        Fn[c][4] = u1.x + d1.x + c0.w + c1.y;
        Fn[c][5] = u1.y + d1.y + c1.x + c1.z;
        Fn[c][6] = u1.z + d1.z + c1.y + c1.w;
        Fn[c][7] = u1.w + d1.w + c1.z + rt;
    }

    // Cross-product epilogue: 4 VALU ops per element per component.
    float o[3][8];
    #pragma unroll
    for (int e = 0; e < 8; ++e) {
        o[0][e] = cA0 * (sc[1][e] * Fn[2][e]) + cB0 * (sc[2][e] * Fn[1][e]);
        o[1][e] = cA1 * (sc[0][e] * Fn[2][e]) + cB1 * (sc[2][e] * Fn[0][e]);
        o[2][e] = cA2 * (sc[0][e] * Fn[1][e]) + cB2 * (sc[1][e] * Fn[0][e]);
    }

    #pragma unroll
    for (int a = 0; a < 3; ++a) {
        float* q = out + baseB + (size_t)a * XY + offC;
        *(float4*)(q)     = make_float4(o[a][0], o[a][1], o[a][2], o[a][3]);
        *(float4*)(q + 4) = make_float4(o[a][4], o[a][5], o[a][6], o[a][7]);
    }
}

extern "C" void kernel_launch(void* const* d_in, const int* in_sizes, int n_in,
                              void* d_out, int out_size, void* d_ws, size_t ws_size,
                              hipStream_t stream)
{
    const float* s   = (const float*)d_in[0];
    // d_in[1] = t (unused: coeff is t-independent with a single cc entry)
    const float* C0p = (const float*)d_in[2];
    const float* Lp  = (const float*)d_in[3];
    float* out = (float*)d_out;

    const int blocks = B * (X / 4);   // 4096 blocks, 256 threads = 4 x-rows each
    psi0_kernel<<<blocks, 256, 0, stream>>>(s, C0p, Lp, out);
}